// Round 4
// baseline (781.020 us; speedup 1.0000x reference)
//
#include <hip/hip_runtime.h>
#include <hip/hip_bf16.h>

// Problem constants (fixed by the reference)
#define BB 2
#define NN 2048
#define KE 48     // neighbors per node
#define CC 128
#define FFD 512
#define K3 384    // 3*C

// bf16 MFMA fragment types (guide §3, HW-verified m89/m91/m92)
typedef short sx8 __attribute__((ext_vector_type(8)));   // 8 bf16 in 4 VGPRs
typedef float fx4 __attribute__((ext_vector_type(4)));   // 4 fp32 acc

__device__ __forceinline__ short f2bs(float f) {
    __bf16 h = (__bf16)f;            // RNE fp32->bf16
    return __builtin_bit_cast(short, h);
}

// Fast exact-quality GELU: erf via Abramowitz-Stegun 7.1.26, |err|<1.5e-7.
__device__ __forceinline__ float gelu_f(float x) {
    float z = fabsf(x) * 0.70710678118654752f;
    float e = __expf(-z * z);
    float t = __builtin_amdgcn_rcpf(fmaf(0.3275911f, z, 1.0f));
    float poly = t * fmaf(t, fmaf(t, fmaf(t, fmaf(t, 1.061405429f, -1.453152027f),
                                          1.421413741f), -0.284496736f), 0.254829592f);
    float erf = 1.0f - poly * e;
    float phi = fmaf(copysignf(erf, x), 0.5f, 0.5f);
    return x * phi;
}

// pack two float4 (already in registers) to bf16x8
__device__ __forceinline__ sx8 pack8(float4 a, float4 b) {
    sx8 r;
    r[0] = f2bs(a.x); r[1] = f2bs(a.y); r[2] = f2bs(a.z); r[3] = f2bs(a.w);
    r[4] = f2bs(b.x); r[5] = f2bs(b.y); r[6] = f2bs(b.z); r[7] = f2bs(b.w);
    return r;
}

// ---------------------------------------------------------------------------
// Transpose + fp32->bf16 convert the 8 weight matrices into ws (unchanged).
// bf16-elem offsets: W1T@0(128x384) W2T@49152(128x128) W3T@65536
// W11T@81920(128x384) W12T@131072 W13T@147456 WinT@163840(512x128)
// WoutT@229376(128x512); total 294912 elems (576KB ws).
// ---------------------------------------------------------------------------
__global__ void prep_weights(const float* __restrict__ W1, const float* __restrict__ W2,
                             const float* __restrict__ W3, const float* __restrict__ W11,
                             const float* __restrict__ W12, const float* __restrict__ W13,
                             const float* __restrict__ Win, const float* __restrict__ Wout,
                             short* __restrict__ wt) {
    int i = blockIdx.x * 256 + threadIdx.x;  // grid covers exactly 294912
    const float* src;
    short* dst;
    int R, S, local;   // R = inner (k) extent of WT; S = row stride of source
    if (i < 49152)       { src = W1;   dst = wt;          R = 384; S = 128; local = i; }
    else if (i < 65536)  { src = W2;   dst = wt + 49152;  R = 128; S = 128; local = i - 49152; }
    else if (i < 81920)  { src = W3;   dst = wt + 65536;  R = 128; S = 128; local = i - 65536; }
    else if (i < 131072) { src = W11;  dst = wt + 81920;  R = 384; S = 128; local = i - 81920; }
    else if (i < 147456) { src = W12;  dst = wt + 131072; R = 128; S = 128; local = i - 131072; }
    else if (i < 163840) { src = W13;  dst = wt + 147456; R = 128; S = 128; local = i - 147456; }
    else if (i < 229376) { src = Win;  dst = wt + 163840; R = 128; S = 512; local = i - 163840; }
    else                 { src = Wout; dst = wt + 229376; R = 512; S = 128; local = i - 229376; }
    int c = local / R;
    int r = local - c * R;
    dst[local] = f2bs(src[r * S + c]);  // WT[c][r] = W[r][c]
}

// ---------------------------------------------------------------------------
// Edge MLP pass -- R7 barrier-free wave-private design.
// Block = 192 threads = 3 waves; wave w owns edge rows [16w, 16w+16).
// Each wave computes ALL 128 output cols for its rows, so the X1/X2
// epilogue->GEMM transposes stay in wave-private LDS (DS in-order within a
// wave -> NO __syncthreads in the whole MLP pipeline).
// ctr row staged once per wave; read as broadcast A-fragment (same LDS addr
// for all 16 m-lanes = conflict-free broadcast) -> full K=384 GEMM1.
// PASS1: 3 barriers for the cross-wave dh reduction only. PASS2: 0 barriers.
// LDS 26928B -> 6 blocks/CU (18 waves). __launch_bounds__(192,5) -> VGPR<=102.
// ---------------------------------------------------------------------------
template <int PASS>
__global__ __launch_bounds__(192, 5) void edge_pass(
    const float* __restrict__ hVsrc, const float* __restrict__ hE,
    const int* __restrict__ Eidx,
    const short* __restrict__ WaT, const float* __restrict__ Wab,
    const short* __restrict__ WbT, const float* __restrict__ Wbb,
    const short* __restrict__ WcT, const float* __restrict__ Wcb,
    const float* __restrict__ mask_att, float* __restrict__ hv1_out,
    const float* __restrict__ gamma, const float* __restrict__ beta,
    float* __restrict__ hE_out) {
    // per-wave region: ctrB 136s (272B) | hEb 16x136s (4352B) | nbrb 16x136s
    __shared__ __align__(16) unsigned char smem[3 * 8976];

    const int tid = threadIdx.x;
    const int w = tid >> 6, lane = tid & 63, q = lane >> 4, m16 = lane & 15;
    const int bn = blockIdx.x;        // b*N+n
    const int bb = bn >> 11;          // batch (N=2048)
    const int rbase = w * 16;         // this wave's first edge row

    short* ctrB = (short*)(smem + w * 8976);
    short* hEb  = (short*)(smem + w * 8976 + 272);   // later reused as X1/X2
    short* nbrb = (short*)(smem + w * 8976 + 4624);
    // PASS1 reduction buffers alias wave0's nbrb (dead after GEMM1; the
    // pre-write __syncthreads guarantees every wave is past GEMM1).
    float* dhp  = (float*)(smem + 4624);             // 384 floats
    float* redp = (float*)(smem + 4624 + 1536);      // 4 floats

    // ---- Eidx first (longest chain), then all staging loads ----
    int e[4];
#pragma unroll
    for (int j = 0; j < 4; ++j) e[j] = Eidx[bn * KE + rbase + j * 4 + q];

    const float* hep = hE + ((size_t)bn * KE + rbase) * CC;
    float4 hl[4][2];
#pragma unroll
    for (int j = 0; j < 4; ++j) {
        const float* p = hep + (j * 4 + q) * CC + m16 * 8;
        hl[j][0] = *(const float4*)p;
        hl[j][1] = *(const float4*)(p + 4);
    }
    const float* ctr = hVsrc + (size_t)bn * CC;
    float4 c0, c1;
    if (lane < 16) {
        c0 = *(const float4*)(ctr + lane * 8);
        c1 = *(const float4*)(ctr + lane * 8 + 4);
    }
    // nbr gather: issue now, consume after 64 MFMAs (ks0-7) hide the latency
    const float* hvb = hVsrc + (size_t)bb * NN * CC;
    float4 nl[4][2];
#pragma unroll
    for (int j = 0; j < 4; ++j) {
        const float* p = hvb + (size_t)e[j] * CC + m16 * 8;
        nl[j][0] = *(const float4*)p;
        nl[j][1] = *(const float4*)(p + 4);
    }
    // pack ctr + hE to LDS (wave-private; no barrier)
    if (lane < 16) *(sx8*)(ctrB + lane * 8) = pack8(c0, c1);
#pragma unroll
    for (int j = 0; j < 4; ++j)
        *(sx8*)(hEb + (j * 4 + q) * 136 + m16 * 8) = pack8(hl[j][0], hl[j][1]);

    // ---- GEMM1: [16x384] @ WaT' -> acc[8 ntiles], K-steps 0..11 ----
    fx4 acc[8];
#pragma unroll
    for (int nt = 0; nt < 8; ++nt)
#pragma unroll
        for (int r = 0; r < 4; ++r) acc[nt][r] = 0.0f;

    const short* waB = WaT + m16 * K3 + q * 8;   // + nt*16*K3 + ks*32
#pragma unroll
    for (int ks = 0; ks < 8; ++ks) {
        sx8 af;
        if (ks < 4) af = *(const sx8*)(ctrB + ks * 32 + q * 8);          // broadcast
        else        af = *(const sx8*)(hEb + m16 * 136 + (ks - 4) * 32 + q * 8);
#pragma unroll
        for (int nt = 0; nt < 8; ++nt) {
            sx8 bf = *(const sx8*)(waB + nt * 16 * K3 + ks * 32);
            acc[nt] = __builtin_amdgcn_mfma_f32_16x16x32_bf16(af, bf, acc[nt], 0, 0, 0);
        }
    }
    // nbr pack -> LDS (loads have had ~64 MFMAs to land)
#pragma unroll
    for (int j = 0; j < 4; ++j)
        *(sx8*)(nbrb + (j * 4 + q) * 136 + m16 * 8) = pack8(nl[j][0], nl[j][1]);
#pragma unroll
    for (int ks = 8; ks < 12; ++ks) {
        sx8 af = *(const sx8*)(nbrb + m16 * 136 + (ks - 8) * 32 + q * 8);
#pragma unroll
        for (int nt = 0; nt < 8; ++nt) {
            sx8 bf = *(const sx8*)(waB + nt * 16 * K3 + ks * 32);
            acc[nt] = __builtin_amdgcn_mfma_f32_16x16x32_bf16(af, bf, acc[nt], 0, 0, 0);
        }
    }

    // ---- epilogue 1: gelu -> X1 (reuses hEb; same-wave in-order DS) ----
    {
        float ba[8];
#pragma unroll
        for (int nt = 0; nt < 8; ++nt) ba[nt] = Wab[nt * 16 + m16];
#pragma unroll
        for (int nt = 0; nt < 8; ++nt)
#pragma unroll
            for (int r = 0; r < 4; ++r)
                hEb[(q * 4 + r) * 136 + nt * 16 + m16] = f2bs(gelu_f(acc[nt][r] + ba[nt]));
    }

    // ---- GEMM2: [16x128] @ WbT' ----
    fx4 acc2[8];
#pragma unroll
    for (int nt = 0; nt < 8; ++nt)
#pragma unroll
        for (int r = 0; r < 4; ++r) acc2[nt][r] = 0.0f;
    const short* wbB = WbT + m16 * CC + q * 8;
#pragma unroll
    for (int kk = 0; kk < 4; ++kk) {
        sx8 af = *(const sx8*)(hEb + m16 * 136 + kk * 32 + q * 8);
#pragma unroll
        for (int nt = 0; nt < 8; ++nt) {
            sx8 bf = *(const sx8*)(wbB + nt * 16 * CC + kk * 32);
            acc2[nt] = __builtin_amdgcn_mfma_f32_16x16x32_bf16(af, bf, acc2[nt], 0, 0, 0);
        }
    }

    // ---- epilogue 2: gelu -> X2 (hEb again) ----
    {
        float bbv[8];
#pragma unroll
        for (int nt = 0; nt < 8; ++nt) bbv[nt] = Wbb[nt * 16 + m16];
#pragma unroll
        for (int nt = 0; nt < 8; ++nt)
#pragma unroll
            for (int r = 0; r < 4; ++r)
                hEb[(q * 4 + r) * 136 + nt * 16 + m16] = f2bs(gelu_f(acc2[nt][r] + bbv[nt]));
    }

    // ---- GEMM3: [16x128] @ WcT' ----
    fx4 acc3[8];
#pragma unroll
    for (int nt = 0; nt < 8; ++nt)
#pragma unroll
        for (int r = 0; r < 4; ++r) acc3[nt][r] = 0.0f;
    const short* wcB = WcT + m16 * CC + q * 8;
#pragma unroll
    for (int kk = 0; kk < 4; ++kk) {
        sx8 af = *(const sx8*)(hEb + m16 * 136 + kk * 32 + q * 8);
#pragma unroll
        for (int nt = 0; nt < 8; ++nt) {
            sx8 bf = *(const sx8*)(wcB + nt * 16 * CC + kk * 32);
            acc3[nt] = __builtin_amdgcn_mfma_f32_16x16x32_bf16(af, bf, acc3[nt], 0, 0, 0);
        }
    }

    float bc[8];
#pragma unroll
    for (int nt = 0; nt < 8; ++nt) bc[nt] = Wcb[nt * 16 + m16];

    if constexpr (PASS == 1) {
        // masked col-sum over this wave's 16 rows, then cross-wave reduce
        float mrow[4];
#pragma unroll
        for (int r = 0; r < 4; ++r) mrow[r] = mask_att[bn * KE + rbase + q * 4 + r];
        float ps[8];
#pragma unroll
        for (int nt = 0; nt < 8; ++nt) {
            float s = 0.f;
#pragma unroll
            for (int r = 0; r < 4; ++r) s += mrow[r] * (acc3[nt][r] + bc[nt]);
            ps[nt] = s;
        }
#pragma unroll
        for (int nt = 0; nt < 8; ++nt) {
            ps[nt] += __shfl_xor(ps[nt], 16);
            ps[nt] += __shfl_xor(ps[nt], 32);
        }
        __syncthreads();   // every wave past GEMM1 -> wave0 nbrb (dhp) dead
        if (q == 0) {
#pragma unroll
            for (int nt = 0; nt < 8; ++nt) dhp[w * 128 + nt * 16 + m16] = ps[nt];
        }
        __syncthreads();
        float val = 0.f;
        if (tid < 128) {
            float dh = dhp[tid] + dhp[128 + tid] + dhp[256 + tid];
            val = hVsrc[(size_t)bn * CC + tid] + dh * (1.0f / 30.0f);
            float sv1 = val, sv2 = val * val;
#pragma unroll
            for (int m = 32; m >= 1; m >>= 1) {
                sv1 += __shfl_xor(sv1, m);
                sv2 += __shfl_xor(sv2, m);
            }
            if ((tid & 63) == 0) {
                redp[(tid >> 6) * 2]     = sv1;
                redp[(tid >> 6) * 2 + 1] = sv2;
            }
        }
        __syncthreads();
        if (tid < 128) {
            float mean = (redp[0] + redp[2]) * (1.0f / 128.0f);
            float var  = (redp[1] + redp[3]) * (1.0f / 128.0f) - mean * mean;
            float rstd = rsqrtf(fmaxf(var, 0.0f) + 1e-5f);
            hv1_out[(size_t)bn * CC + tid] = gamma[tid] * (val - mean) * rstd + beta[tid];
        }
    } else {
        // residual + per-row LN, fully in registers (zero barriers)
        const float* hres = hE + ((size_t)bn * KE + rbase) * CC;
        float x[8][4];
#pragma unroll
        for (int nt = 0; nt < 8; ++nt)
#pragma unroll
            for (int r = 0; r < 4; ++r)
                x[nt][r] = hres[(q * 4 + r) * CC + nt * 16 + m16] + acc3[nt][r] + bc[nt];
        float s1[4], s2[4];
#pragma unroll
        for (int r = 0; r < 4; ++r) {
            float a = 0.f, b2s = 0.f;
#pragma unroll
            for (int nt = 0; nt < 8; ++nt) { a += x[nt][r]; b2s += x[nt][r] * x[nt][r]; }
            s1[r] = a; s2[r] = b2s;
        }
#pragma unroll
        for (int r = 0; r < 4; ++r) {
#pragma unroll
            for (int m = 8; m >= 1; m >>= 1) {    // reduce across the 16 m-lanes
                s1[r] += __shfl_xor(s1[r], m);
                s2[r] += __shfl_xor(s2[r], m);
            }
        }
        float gg[8], gb[8];
#pragma unroll
        for (int nt = 0; nt < 8; ++nt) {
            gg[nt] = gamma[nt * 16 + m16];
            gb[nt] = beta[nt * 16 + m16];
        }
#pragma unroll
        for (int r = 0; r < 4; ++r) {
            float mean = s1[r] * (1.0f / 128.0f);
            float var  = s2[r] * (1.0f / 128.0f) - mean * mean;
            float rstd = rsqrtf(fmaxf(var, 0.0f) + 1e-5f);
            float* orow = hE_out + ((size_t)bn * KE + rbase + q * 4 + r) * CC;
#pragma unroll
            for (int nt = 0; nt < 8; ++nt)
                orow[nt * 16 + m16] = gg[nt] * (x[nt][r] - mean) * rstd + gb[nt];
        }
    }
}

// ---------------------------------------------------------------------------
// MFMA FFN: 16 nodes per block (grid 256 = 1 block/CU, 256 thr = 4 waves).
// __launch_bounds__(256,1): occupancy fixed at 1 block/CU, VGPRs free;
// ALL B-fragments prefetched to registers (no in-loop global stalls).
// ---------------------------------------------------------------------------
__global__ __launch_bounds__(256, 1) void ffn_kernel(
    float* __restrict__ hv, const short* __restrict__ WinT,
    const float* __restrict__ Winb, const short* __restrict__ WoutT,
    const float* __restrict__ Woutb, const float* __restrict__ g2,
    const float* __restrict__ b2, const float* __restrict__ maskV) {
    __shared__ __align__(16) float hvF[16 * 132];   // fp32 residual / LN buffer
    __shared__ __align__(16) short Abf[16 * 136];   // bf16 A for GEMM1
    __shared__ __align__(16) short Xs[16 * 520];    // bf16 hidden for GEMM2

    const int tid = threadIdx.x;
    const int bn  = blockIdx.x;       // node tile: nodes [bn*16, bn*16+16)
    const int wave = tid >> 6, lane = tid & 63, q = lane >> 4, m16 = lane & 15;
    const int col0 = wave * 32 + m16, col1 = col0 + 16;

    // ---- prefetch ALL GEMM1 B-frags (this wave's 128 cols x K=128) ----
    sx8 bw[4][8];
#pragma unroll
    for (int kk = 0; kk < 4; ++kk)
#pragma unroll
        for (int nt = 0; nt < 8; ++nt)
            bw[kk][nt] = *(const sx8*)(WinT + (wave * 128 + nt * 16 + m16) * CC + kk * 32 + q * 8);

    // ---- stage hv tile: fp32 copy + bf16 copy ----
    for (int i = tid; i < 512; i += 256) {          // 512 float4 chunks
        int row = i >> 5;                            // 32 chunks/row
        int c4  = (i & 31) * 4;
        float4 v = *(const float4*)(hv + (bn * 16 + row) * CC + c4);
        hvF[row * 132 + c4]     = v.x;
        hvF[row * 132 + c4 + 1] = v.y;
        hvF[row * 132 + c4 + 2] = v.z;
        hvF[row * 132 + c4 + 3] = v.w;
        Abf[row * 136 + c4]     = f2bs(v.x);
        Abf[row * 136 + c4 + 1] = f2bs(v.y);
        Abf[row * 136 + c4 + 2] = f2bs(v.z);
        Abf[row * 136 + c4 + 3] = f2bs(v.w);
    }
    __syncthreads();

    // ---- GEMM1: hidden cols [128w, 128w+128) (B all in registers) ----
    fx4 acc1[8];
#pragma unroll
    for (int nt = 0; nt < 8; ++nt)
#pragma unroll
        for (int r = 0; r < 4; ++r) acc1[nt][r] = 0.0f;

#pragma unroll
    for (int kk = 0; kk < 4; ++kk) {
        sx8 af = *(const sx8*)(Abf + m16 * 136 + kk * 32 + q * 8);
#pragma unroll
        for (int nt = 0; nt < 8; ++nt)
            acc1[nt] = __builtin_amdgcn_mfma_f32_16x16x32_bf16(af, bw[kk][nt], acc1[nt], 0, 0, 0);
    }

    // ---- prefetch ALL GEMM2 B-frags (overlap epilogue + barrier) ----
    sx8 c0a[16], c1a[16];
#pragma unroll
    for (int kk = 0; kk < 16; ++kk) {
        c0a[kk] = *(const sx8*)(WoutT + col0 * FFD + kk * 32 + q * 8);
        c1a[kk] = *(const sx8*)(WoutT + col1 * FFD + kk * 32 + q * 8);
    }

#pragma unroll
    for (int nt = 0; nt < 8; ++nt) {
        int coln = wave * 128 + nt * 16 + m16;
        float bi = Winb[coln];
#pragma unroll
        for (int r = 0; r < 4; ++r) {
            int row = q * 4 + r;
            Xs[row * 520 + coln] = f2bs(gelu_f(acc1[nt][r] + bi));
        }
    }
    __syncthreads();

    // ---- GEMM2: out cols [32w, 32w+32) (B all in registers) ----
    fx4 o0, o1;
#pragma unroll
    for (int r = 0; r < 4; ++r) { o0[r] = 0.0f; o1[r] = 0.0f; }
#pragma unroll
    for (int kk = 0; kk < 16; ++kk) {
        sx8 af = *(const sx8*)(Xs + m16 * 520 + kk * 32 + q * 8);
        o0 = __builtin_amdgcn_mfma_f32_16x16x32_bf16(af, c0a[kk], o0, 0, 0, 0);
        o1 = __builtin_amdgcn_mfma_f32_16x16x32_bf16(af, c1a[kk], o1, 0, 0, 0);
    }
    {
        float bo0 = Woutb[col0], bo1 = Woutb[col1];
#pragma unroll
        for (int r = 0; r < 4; ++r) {
            int row = q * 4 + r;
            hvF[row * 132 + col0] += o0[r] + bo0;
            hvF[row * 132 + col1] += o1[r] + bo1;
        }
    }
    __syncthreads();

    // ---- per-node LN2 + mask, write back ----
    int g = tid >> 5, l32 = tid & 31;
#pragma unroll
    for (int rr = 0; rr < 2; ++rr) {
        int row = g + rr * 8;
        float x0 = hvF[row * 132 + l32];
        float x1 = hvF[row * 132 + l32 + 32];
        float x2 = hvF[row * 132 + l32 + 64];
        float x3 = hvF[row * 132 + l32 + 96];
        float s1 = x0 + x1 + x2 + x3;
        float s2 = x0 * x0 + x1 * x1 + x2 * x2 + x3 * x3;
#pragma unroll
        for (int m = 16; m >= 1; m >>= 1) {
            s1 += __shfl_xor(s1, m, 32);
            s2 += __shfl_xor(s2, m, 32);
        }
        float mean = s1 * (1.0f / 128.0f);
        float var  = s2 * (1.0f / 128.0f) - mean * mean;
        float rstd = rsqrtf(fmaxf(var, 0.0f) + 1e-5f);
        int node = bn * 16 + row;
        float mk = maskV[node];
        float* orow = hv + node * CC;
        orow[l32]      = mk * (g2[l32] * (x0 - mean) * rstd + b2[l32]);
        orow[l32 + 32] = mk * (g2[l32 + 32] * (x1 - mean) * rstd + b2[l32 + 32]);
        orow[l32 + 64] = mk * (g2[l32 + 64] * (x2 - mean) * rstd + b2[l32 + 64]);
        orow[l32 + 96] = mk * (g2[l32 + 96] * (x3 - mean) * rstd + b2[l32 + 96]);
    }
}

extern "C" void kernel_launch(void* const* d_in, const int* in_sizes, int n_in,
                              void* d_out, int out_size, void* d_ws, size_t ws_size,
                              hipStream_t stream) {
    (void)in_sizes; (void)n_in; (void)out_size; (void)ws_size;
    const float* hV    = (const float*)d_in[0];
    const float* hE    = (const float*)d_in[1];
    const int*   Eidx  = (const int*)d_in[2];
    const float* maskV = (const float*)d_in[3];
    const float* maskA = (const float*)d_in[4];
    const float* W1w  = (const float*)d_in[5];
    const float* W1b  = (const float*)d_in[6];
    const float* W2w  = (const float*)d_in[7];
    const float* W2b  = (const float*)d_in[8];
    const float* W3w  = (const float*)d_in[9];
    const float* W3b  = (const float*)d_in[10];
    const float* W11w = (const float*)d_in[11];
    const float* W11b = (const float*)d_in[12];
    const float* W12w = (const float*)d_in[13];
    const float* W12b = (const float*)d_in[14];
    const float* W13w = (const float*)d_in[15];
    const float* W13b = (const float*)d_in[16];
    const float* Winw = (const float*)d_in[17];
    const float* Winb = (const float*)d_in[18];
    const float* Woutw = (const float*)d_in[19];
    const float* Woutb = (const float*)d_in[20];
    const float* g1 = (const float*)d_in[21];
    const float* b1 = (const float*)d_in[22];
    const float* g2 = (const float*)d_in[23];
    const float* b2 = (const float*)d_in[24];
    const float* g3 = (const float*)d_in[25];
    const float* b3 = (const float*)d_in[26];

    short* wt   = (short*)d_ws;                 // 294912 bf16 = 576KB
    float* outV = (float*)d_out;                // h_V region [4096,128]
    float* outE = outV + (size_t)BB * NN * CC;  // h_E region [4096,48,128]

    prep_weights<<<1152, 256, 0, stream>>>(W1w, W2w, W3w, W11w, W12w, W13w, Winw, Woutw, wt);
    edge_pass<1><<<BB * NN, 192, 0, stream>>>(hV, hE, Eidx,
                                              wt, W1b, wt + 49152, W2b, wt + 65536, W3b,
                                              maskA, outV, g1, b1, nullptr);
    ffn_kernel<<<256, 256, 0, stream>>>(outV, wt + 163840, Winb, wt + 229376, Woutb, g2, b2, maskV);
    edge_pass<2><<<BB * NN, 192, 0, stream>>>(outV, hE, Eidx,
                                              wt + 81920, W11b, wt + 131072, W12b, wt + 147456, W13b,
                                              nullptr, nullptr, g3, b3, outE);
}

// Round 5
// 348.946 us; speedup vs baseline: 2.2382x; 2.2382x over previous
//
#include <hip/hip_runtime.h>
#include <hip/hip_bf16.h>

// Problem constants (fixed by the reference)
#define BB 2
#define NN 2048
#define KE 48     // neighbors per node
#define CC 128
#define FFD 512
#define K3 384    // 3*C (full weight row stride in WT layout)

// bf16 MFMA fragment types (guide §3, HW-verified m89/m91/m92)
typedef short sx8 __attribute__((ext_vector_type(8)));   // 8 bf16 in 4 VGPRs
typedef float fx4 __attribute__((ext_vector_type(4)));   // 4 fp32 acc

__device__ __forceinline__ short f2bs(float f) {
    __bf16 h = (__bf16)f;            // RNE fp32->bf16
    return __builtin_bit_cast(short, h);
}

// Fast exact-quality GELU: erf via Abramowitz-Stegun 7.1.26, |err|<1.5e-7.
__device__ __forceinline__ float gelu_f(float x) {
    float z = fabsf(x) * 0.70710678118654752f;
    float e = __expf(-z * z);
    float t = __builtin_amdgcn_rcpf(fmaf(0.3275911f, z, 1.0f));
    float poly = t * fmaf(t, fmaf(t, fmaf(t, fmaf(t, 1.061405429f, -1.453152027f),
                                          1.421413741f), -0.284496736f), 0.254829592f);
    float erf = 1.0f - poly * e;
    float phi = fmaf(copysignf(erf, x), 0.5f, 0.5f);
    return x * phi;
}

// load 8 consecutive fp32 (32B aligned) and convert to bf16x8 (as short8)
__device__ __forceinline__ sx8 cvt8f(const float* p) {
    float4 a = *(const float4*)p;
    float4 b = *(const float4*)(p + 4);
    sx8 r;
    r[0] = f2bs(a.x); r[1] = f2bs(a.y); r[2] = f2bs(a.z); r[3] = f2bs(a.w);
    r[4] = f2bs(b.x); r[5] = f2bs(b.y); r[6] = f2bs(b.z); r[7] = f2bs(b.w);
    return r;
}

// pack two float4 (already in registers) to bf16x8
__device__ __forceinline__ sx8 pack8(float4 a, float4 b) {
    sx8 r;
    r[0] = f2bs(a.x); r[1] = f2bs(a.y); r[2] = f2bs(a.z); r[3] = f2bs(a.w);
    r[4] = f2bs(b.x); r[5] = f2bs(b.y); r[6] = f2bs(b.z); r[7] = f2bs(b.w);
    return r;
}

// ---------------------------------------------------------------------------
// Transpose + fp32->bf16 convert the 8 weight matrices into ws (unchanged).
// bf16-elem offsets: W1T@0(128x384) W2T@49152(128x128) W3T@65536
// W11T@81920(128x384) W12T@131072 W13T@147456 WinT@163840(512x128)
// WoutT@229376(128x512); total 294912 elems (576KB); Pc/Pn fp32 follow.
// ---------------------------------------------------------------------------
__global__ void prep_weights(const float* __restrict__ W1, const float* __restrict__ W2,
                             const float* __restrict__ W3, const float* __restrict__ W11,
                             const float* __restrict__ W12, const float* __restrict__ W13,
                             const float* __restrict__ Win, const float* __restrict__ Wout,
                             short* __restrict__ wt) {
    int i = blockIdx.x * 256 + threadIdx.x;  // grid covers exactly 294912
    const float* src;
    short* dst;
    int R, S, local;   // R = inner (k) extent of WT; S = row stride of source
    if (i < 49152)       { src = W1;   dst = wt;          R = 384; S = 128; local = i; }
    else if (i < 65536)  { src = W2;   dst = wt + 49152;  R = 128; S = 128; local = i - 49152; }
    else if (i < 81920)  { src = W3;   dst = wt + 65536;  R = 128; S = 128; local = i - 65536; }
    else if (i < 131072) { src = W11;  dst = wt + 81920;  R = 384; S = 128; local = i - 81920; }
    else if (i < 147456) { src = W12;  dst = wt + 131072; R = 128; S = 128; local = i - 131072; }
    else if (i < 163840) { src = W13;  dst = wt + 147456; R = 128; S = 128; local = i - 147456; }
    else if (i < 229376) { src = Win;  dst = wt + 163840; R = 128; S = 512; local = i - 163840; }
    else                 { src = Wout; dst = wt + 229376; R = 512; S = 128; local = i - 229376; }
    int c = local / R;
    int r = local - c * R;
    dst[local] = f2bs(src[r * S + c]);  // WT[c][r] = W[r][c]
}

// ---------------------------------------------------------------------------
// Precompute node projections for one edge pass:
//   Pc[n][c] = hv[n] @ W[0:128][c]   + bias[c]     (ctr part of concat, +b)
//   Pn[n][c] = hv[n] @ W[256:384][c]               (nbr part of concat)
// 16 nodes per block, grid 256; wave w covers cols [32w, 32w+32) for both.
// ---------------------------------------------------------------------------
__global__ __launch_bounds__(256) void precompute_P(
    const float* __restrict__ hv, const short* __restrict__ WT,
    const float* __restrict__ bias, float* __restrict__ Pc,
    float* __restrict__ Pn) {
    __shared__ __align__(16) short Abf[16 * 136];
    const int tid = threadIdx.x;
    const int bn  = blockIdx.x;       // node tile [bn*16, bn*16+16)
    const int wave = tid >> 6, lane = tid & 63, q = lane >> 4, m16 = lane & 15;
    const int col0 = wave * 32 + m16, col1 = col0 + 16;

    {   // stage 16x128 A-tile as bf16: one sx8 per thread
        int row = tid >> 4, seg = tid & 15;
        Abf[row * 136 + seg * 8 + 0] = 0;  // (dummy to keep layout obvious)
        *(sx8*)(Abf + row * 136 + seg * 8) = cvt8f(hv + (size_t)(bn * 16 + row) * CC + seg * 8);
    }
    __syncthreads();

    fx4 c0, c1, n0, n1;
#pragma unroll
    for (int r = 0; r < 4; ++r) { c0[r] = 0.f; c1[r] = 0.f; n0[r] = 0.f; n1[r] = 0.f; }
#pragma unroll
    for (int kk = 0; kk < 4; ++kk) {
        sx8 af = *(const sx8*)(Abf + m16 * 136 + kk * 32 + q * 8);
        sx8 bc0 = *(const sx8*)(WT + col0 * K3 + kk * 32 + q * 8);
        sx8 bc1 = *(const sx8*)(WT + col1 * K3 + kk * 32 + q * 8);
        sx8 bn0 = *(const sx8*)(WT + col0 * K3 + 256 + kk * 32 + q * 8);
        sx8 bn1 = *(const sx8*)(WT + col1 * K3 + 256 + kk * 32 + q * 8);
        c0 = __builtin_amdgcn_mfma_f32_16x16x32_bf16(af, bc0, c0, 0, 0, 0);
        c1 = __builtin_amdgcn_mfma_f32_16x16x32_bf16(af, bc1, c1, 0, 0, 0);
        n0 = __builtin_amdgcn_mfma_f32_16x16x32_bf16(af, bn0, n0, 0, 0, 0);
        n1 = __builtin_amdgcn_mfma_f32_16x16x32_bf16(af, bn1, n1, 0, 0, 0);
    }
    float bi0 = bias[col0], bi1 = bias[col1];
#pragma unroll
    for (int r = 0; r < 4; ++r) {
        int node = bn * 16 + q * 4 + r;
        Pc[(size_t)node * CC + col0] = c0[r] + bi0;
        Pc[(size_t)node * CC + col1] = c1[r] + bi1;
        Pn[(size_t)node * CC + col0] = n0[r];
        Pn[(size_t)node * CC + col1] = n1[r];
    }
}

// ---------------------------------------------------------------------------
// Edge MLP pass -- R8: R3 skeleton (proven 113us) + algebraic K-cut.
// GEMM1 is now [48x128] over hE only (W1 rows 128..255); the ctr and nbr
// contributions come from precomputed Pc[bn]/Pn[e] added in epilogue 1
// (gathers issued at block top -> consumed after GEMM1: full latency slack).
// MFMA/wave 104->72; staging halved (no ctr/nbr pack); PASS1 LDS 15KB.
// ---------------------------------------------------------------------------
template <int PASS>
__global__ __launch_bounds__(256, 5) void edge_pass(
    const float* __restrict__ hVsrc, const float* __restrict__ hE,
    const int* __restrict__ Eidx,
    const short* __restrict__ WaT,
    const short* __restrict__ WbT, const float* __restrict__ Wbb,
    const short* __restrict__ WcT, const float* __restrict__ Wcb,
    const float* __restrict__ Pc, const float* __restrict__ Pn,
    const float* __restrict__ mask_att, float* __restrict__ hv1_out,
    const float* __restrict__ gamma, const float* __restrict__ beta,
    float* __restrict__ hE_out) {
    // PASS1: A0/Xs 13056 | dhp 2048 | red 16  = 15120
    // PASS2: max(A0/Xs 13056, S 48x132 fp32 25344) = 25344
    __shared__ __align__(16) unsigned char smem_raw[PASS == 1 ? 15120 : 25344];

    short* A0   = (short*)smem_raw;          // 48x136 bf16 hE tile
    short* Xs   = (short*)smem_raw;          // aliases A0 after GEMM1
    float* S    = (float*)smem_raw;          // PASS2 epilogue (48x132 fp32)
    float* dhp  = (float*)(smem_raw + 13056);
    float* redp = (float*)(smem_raw + 15104);

    const int tid = threadIdx.x;
    const int bn  = blockIdx.x;       // b*N+n
    const int bb  = bn >> 11;         // batch (N=2048)
    const int wave = tid >> 6, lane = tid & 63, q = lane >> 4, m16 = lane & 15;
    const int col0 = wave * 32 + m16; // ntile 2*wave
    const int col1 = col0 + 16;       // ntile 2*wave+1
    const int r0 = tid >> 4, seg = tid & 15;

    // ---- Eidx for this lane's 12 acc rows (row = mt*16 + q*4 + r) ----
    int e[3][4];
#pragma unroll
    for (int mt = 0; mt < 3; ++mt)
#pragma unroll
        for (int r = 0; r < 4; ++r)
            e[mt][r] = Eidx[bn * KE + mt * 16 + q * 4 + r];

    // ---- Pc / Pn gathers: issued now, consumed at epilogue 1 ----
    float pc0 = Pc[(size_t)bn * CC + col0];
    float pc1 = Pc[(size_t)bn * CC + col1];
    float pn0[3][4], pn1[3][4];
#pragma unroll
    for (int mt = 0; mt < 3; ++mt)
#pragma unroll
        for (int r = 0; r < 4; ++r) {
            size_t prow = ((size_t)bb * NN + e[mt][r]) * CC;
            pn0[mt][r] = Pn[prow + col0];
            pn1[mt][r] = Pn[prow + col1];
        }

    // ---- stage A0 = hE tile (3 rows/thread, 6 float4 loads batched) ----
    {
        const float* he = hE + (size_t)bn * KE * CC + seg * 8;
        float4 h0a = *(const float4*)(he + r0 * CC);
        float4 h0b = *(const float4*)(he + r0 * CC + 4);
        float4 h1a = *(const float4*)(he + (r0 + 16) * CC);
        float4 h1b = *(const float4*)(he + (r0 + 16) * CC + 4);
        float4 h2a = *(const float4*)(he + (r0 + 32) * CC);
        float4 h2b = *(const float4*)(he + (r0 + 32) * CC + 4);
        *(sx8*)(A0 + r0 * 136 + seg * 8)        = pack8(h0a, h0b);
        *(sx8*)(A0 + (r0 + 16) * 136 + seg * 8) = pack8(h1a, h1b);
        *(sx8*)(A0 + (r0 + 32) * 136 + seg * 8) = pack8(h2a, h2b);
    }

    // ---- prefetch GEMM1 B-frags: W1 rows 128..255 (hE block) ----
    sx8 b0[4], b1[4];
#pragma unroll
    for (int kk = 0; kk < 4; ++kk) {
        b0[kk] = *(const sx8*)(WaT + col0 * K3 + 128 + kk * 32 + q * 8);
        b1[kk] = *(const sx8*)(WaT + col1 * K3 + 128 + kk * 32 + q * 8);
    }
    __syncthreads();   // A0 staged

    // ---- GEMM1: [48x128] over hE ----
    fx4 acc[3][2];
#pragma unroll
    for (int mt = 0; mt < 3; ++mt)
#pragma unroll
        for (int nt = 0; nt < 2; ++nt)
#pragma unroll
            for (int r = 0; r < 4; ++r) acc[mt][nt][r] = 0.0f;
#pragma unroll
    for (int kk = 0; kk < 4; ++kk) {
#pragma unroll
        for (int mt = 0; mt < 3; ++mt) {
            sx8 af = *(const sx8*)(A0 + (mt * 16 + m16) * 136 + kk * 32 + q * 8);
            acc[mt][0] = __builtin_amdgcn_mfma_f32_16x16x32_bf16(af, b0[kk], acc[mt][0], 0, 0, 0);
            acc[mt][1] = __builtin_amdgcn_mfma_f32_16x16x32_bf16(af, b1[kk], acc[mt][1], 0, 0, 0);
        }
    }

    // ---- prefetch GEMM2 B-frags (hide L2 latency under barrier+epi1) ----
    sx8 p0[4], p1[4];
#pragma unroll
    for (int kk = 0; kk < 4; ++kk) {
        p0[kk] = *(const sx8*)(WbT + col0 * CC + kk * 32 + q * 8);
        p1[kk] = *(const sx8*)(WbT + col1 * CC + kk * 32 + q * 8);
    }
    __syncthreads();   // all waves done reading A0 (Xs aliases it)

    // ---- epilogue 1: acc + Pc + Pn -> gelu -> Xs ----
#pragma unroll
    for (int mt = 0; mt < 3; ++mt)
#pragma unroll
        for (int r = 0; r < 4; ++r) {
            int row = mt * 16 + q * 4 + r;
            Xs[row * 136 + col0] = f2bs(gelu_f(acc[mt][0][r] + pc0 + pn0[mt][r]));
            Xs[row * 136 + col1] = f2bs(gelu_f(acc[mt][1][r] + pc1 + pn1[mt][r]));
        }
    __syncthreads();   // Xs ready

    // ---- GEMM2: [48x128] @ WbT' ----
    fx4 acc2[3][2];
#pragma unroll
    for (int mt = 0; mt < 3; ++mt)
#pragma unroll
        for (int nt = 0; nt < 2; ++nt)
#pragma unroll
            for (int r = 0; r < 4; ++r) acc2[mt][nt][r] = 0.0f;
#pragma unroll
    for (int kk = 0; kk < 4; ++kk) {
#pragma unroll
        for (int mt = 0; mt < 3; ++mt) {
            sx8 af = *(const sx8*)(Xs + (mt * 16 + m16) * 136 + kk * 32 + q * 8);
            acc2[mt][0] = __builtin_amdgcn_mfma_f32_16x16x32_bf16(af, p0[kk], acc2[mt][0], 0, 0, 0);
            acc2[mt][1] = __builtin_amdgcn_mfma_f32_16x16x32_bf16(af, p1[kk], acc2[mt][1], 0, 0, 0);
        }
    }

    // ---- prefetch GEMM3 B-frags + pass-specific operands ----
    sx8 t0[4], t1[4];
#pragma unroll
    for (int kk = 0; kk < 4; ++kk) {
        t0[kk] = *(const sx8*)(WcT + col0 * CC + kk * 32 + q * 8);
        t1[kk] = *(const sx8*)(WcT + col1 * CC + kk * 32 + q * 8);
    }
    float mrow[12];
    float res0[12], res1[12];
    if constexpr (PASS == 1) {
#pragma unroll
        for (int mt = 0; mt < 3; ++mt)
#pragma unroll
            for (int r = 0; r < 4; ++r)
                mrow[mt * 4 + r] = mask_att[bn * KE + mt * 16 + q * 4 + r];
    } else {
#pragma unroll
        for (int mt = 0; mt < 3; ++mt)
#pragma unroll
            for (int r = 0; r < 4; ++r) {
                int row = mt * 16 + q * 4 + r;
                res0[mt * 4 + r] = hE[((size_t)bn * KE + row) * CC + col0];
                res1[mt * 4 + r] = hE[((size_t)bn * KE + row) * CC + col1];
            }
    }
    __syncthreads();  // all waves done reading X1

    // ---- epilogue 2: gelu -> Xs (in place) ----
    {
        float bb0 = Wbb[col0], bb1 = Wbb[col1];
#pragma unroll
        for (int mt = 0; mt < 3; ++mt)
#pragma unroll
            for (int r = 0; r < 4; ++r) {
                int row = mt * 16 + q * 4 + r;
                Xs[row * 136 + col0] = f2bs(gelu_f(acc2[mt][0][r] + bb0));
                Xs[row * 136 + col1] = f2bs(gelu_f(acc2[mt][1][r] + bb1));
            }
    }
    __syncthreads();   // Xs ready

    // ---- GEMM3: [48x128] @ WcT' (bias in epilogue) ----
    fx4 acc3[3][2];
#pragma unroll
    for (int mt = 0; mt < 3; ++mt)
#pragma unroll
        for (int nt = 0; nt < 2; ++nt)
#pragma unroll
            for (int r = 0; r < 4; ++r) acc3[mt][nt][r] = 0.0f;
#pragma unroll
    for (int kk = 0; kk < 4; ++kk) {
#pragma unroll
        for (int mt = 0; mt < 3; ++mt) {
            sx8 af = *(const sx8*)(Xs + (mt * 16 + m16) * 136 + kk * 32 + q * 8);
            acc3[mt][0] = __builtin_amdgcn_mfma_f32_16x16x32_bf16(af, t0[kk], acc3[mt][0], 0, 0, 0);
            acc3[mt][1] = __builtin_amdgcn_mfma_f32_16x16x32_bf16(af, t1[kk], acc3[mt][1], 0, 0, 0);
        }
    }

    float bc0 = Wcb[col0], bc1 = Wcb[col1];

    if constexpr (PASS == 1) {
        // masked sum over the 48 edge rows -> dh[col]
        float ps0 = 0.f, ps1 = 0.f;
#pragma unroll
        for (int mt = 0; mt < 3; ++mt)
#pragma unroll
            for (int r = 0; r < 4; ++r) {
                float m = mrow[mt * 4 + r];
                ps0 += m * (acc3[mt][0][r] + bc0);
                ps1 += m * (acc3[mt][1][r] + bc1);
            }
        // dhp sits ABOVE Xs -> disjoint from GEMM3 reads
        dhp[q * 128 + col0] = ps0;
        dhp[q * 128 + col1] = ps1;
        __syncthreads();
        float val = 0.f;
        if (tid < 128) {
            float dh = dhp[tid] + dhp[128 + tid] + dhp[256 + tid] + dhp[384 + tid];
            val = hVsrc[(size_t)bn * CC + tid] + dh * (1.0f / 30.0f);
            float sv1 = val, sv2 = val * val;
#pragma unroll
            for (int m = 32; m >= 1; m >>= 1) {
                sv1 += __shfl_xor(sv1, m);
                sv2 += __shfl_xor(sv2, m);
            }
            if ((tid & 63) == 0) {
                redp[(tid >> 6) * 2]     = sv1;
                redp[(tid >> 6) * 2 + 1] = sv2;
            }
        }
        __syncthreads();
        if (tid < 128) {
            float mean = (redp[0] + redp[2]) * (1.0f / 128.0f);
            float var  = (redp[1] + redp[3]) * (1.0f / 128.0f) - mean * mean;
            float rstd = rsqrtf(fmaxf(var, 0.0f) + 1e-5f);
            hv1_out[(size_t)bn * CC + tid] = gamma[tid] * (val - mean) * rstd + beta[tid];
        }
    } else {
        __syncthreads();  // all waves done reading Xs (S overwrites it)
        // S = hE + msg (fp32)
#pragma unroll
        for (int mt = 0; mt < 3; ++mt)
#pragma unroll
            for (int r = 0; r < 4; ++r) {
                int row = mt * 16 + q * 4 + r;
                S[row * 132 + col0] = res0[mt * 4 + r] + acc3[mt][0][r] + bc0;
                S[row * 132 + col1] = res1[mt * 4 + r] + acc3[mt][1][r] + bc1;
            }
        __syncthreads();
        // per-edge-row LayerNorm; 8 groups of 32 lanes, 6 rows each
        int g = tid >> 5, l32 = tid & 31;
        for (int r = g; r < 48; r += 8) {
            float x0 = S[r * 132 + l32];
            float x1 = S[r * 132 + l32 + 32];
            float x2 = S[r * 132 + l32 + 64];
            float x3 = S[r * 132 + l32 + 96];
            float sv1 = x0 + x1 + x2 + x3;
            float sv2 = x0 * x0 + x1 * x1 + x2 * x2 + x3 * x3;
#pragma unroll
            for (int m = 16; m >= 1; m >>= 1) {
                sv1 += __shfl_xor(sv1, m, 32);
                sv2 += __shfl_xor(sv2, m, 32);
            }
            float mean = sv1 * (1.0f / 128.0f);
            float var  = sv2 * (1.0f / 128.0f) - mean * mean;
            float rstd = rsqrtf(fmaxf(var, 0.0f) + 1e-5f);
            float* orow = hE_out + ((size_t)bn * KE + r) * CC;
            orow[l32]      = gamma[l32] * (x0 - mean) * rstd + beta[l32];
            orow[l32 + 32] = gamma[l32 + 32] * (x1 - mean) * rstd + beta[l32 + 32];
            orow[l32 + 64] = gamma[l32 + 64] * (x2 - mean) * rstd + beta[l32 + 64];
            orow[l32 + 96] = gamma[l32 + 96] * (x3 - mean) * rstd + beta[l32 + 96];
        }
    }
}

// ---------------------------------------------------------------------------
// MFMA FFN: 16 nodes per block (grid 256 = 1 block/CU, 256 thr = 4 waves).
// __launch_bounds__(256,1): occupancy fixed at 1 block/CU, VGPRs free;
// ALL B-fragments prefetched to registers (no in-loop global stalls).
// ---------------------------------------------------------------------------
__global__ __launch_bounds__(256, 1) void ffn_kernel(
    float* __restrict__ hv, const short* __restrict__ WinT,
    const float* __restrict__ Winb, const short* __restrict__ WoutT,
    const float* __restrict__ Woutb, const float* __restrict__ g2,
    const float* __restrict__ b2, const float* __restrict__ maskV) {
    __shared__ __align__(16) float hvF[16 * 132];   // fp32 residual / LN buffer
    __shared__ __align__(16) short Abf[16 * 136];   // bf16 A for GEMM1
    __shared__ __align__(16) short Xs[16 * 520];    // bf16 hidden for GEMM2

    const int tid = threadIdx.x;
    const int bn  = blockIdx.x;       // node tile: nodes [bn*16, bn*16+16)
    const int wave = tid >> 6, lane = tid & 63, q = lane >> 4, m16 = lane & 15;
    const int col0 = wave * 32 + m16, col1 = col0 + 16;

    // ---- prefetch ALL GEMM1 B-frags (this wave's 128 cols x K=128) ----
    sx8 bw[4][8];
#pragma unroll
    for (int kk = 0; kk < 4; ++kk)
#pragma unroll
        for (int nt = 0; nt < 8; ++nt)
            bw[kk][nt] = *(const sx8*)(WinT + (wave * 128 + nt * 16 + m16) * CC + kk * 32 + q * 8);

    // ---- stage hv tile: fp32 copy + bf16 copy ----
    for (int i = tid; i < 512; i += 256) {          // 512 float4 chunks
        int row = i >> 5;                            // 32 chunks/row
        int c4  = (i & 31) * 4;
        float4 v = *(const float4*)(hv + (bn * 16 + row) * CC + c4);
        hvF[row * 132 + c4]     = v.x;
        hvF[row * 132 + c4 + 1] = v.y;
        hvF[row * 132 + c4 + 2] = v.z;
        hvF[row * 132 + c4 + 3] = v.w;
        Abf[row * 136 + c4]     = f2bs(v.x);
        Abf[row * 136 + c4 + 1] = f2bs(v.y);
        Abf[row * 136 + c4 + 2] = f2bs(v.z);
        Abf[row * 136 + c4 + 3] = f2bs(v.w);
    }
    __syncthreads();

    // ---- GEMM1: hidden cols [128w, 128w+128) (B all in registers) ----
    fx4 acc1[8];
#pragma unroll
    for (int nt = 0; nt < 8; ++nt)
#pragma unroll
        for (int r = 0; r < 4; ++r) acc1[nt][r] = 0.0f;

#pragma unroll
    for (int kk = 0; kk < 4; ++kk) {
        sx8 af = *(const sx8*)(Abf + m16 * 136 + kk * 32 + q * 8);
#pragma unroll
        for (int nt = 0; nt < 8; ++nt)
            acc1[nt] = __builtin_amdgcn_mfma_f32_16x16x32_bf16(af, bw[kk][nt], acc1[nt], 0, 0, 0);
    }

    // ---- prefetch ALL GEMM2 B-frags (overlap epilogue + barrier) ----
    sx8 c0a[16], c1a[16];
#pragma unroll
    for (int kk = 0; kk < 16; ++kk) {
        c0a[kk] = *(const sx8*)(WoutT + col0 * FFD + kk * 32 + q * 8);
        c1a[kk] = *(const sx8*)(WoutT + col1 * FFD + kk * 32 + q * 8);
    }

#pragma unroll
    for (int nt = 0; nt < 8; ++nt) {
        int coln = wave * 128 + nt * 16 + m16;
        float bi = Winb[coln];
#pragma unroll
        for (int r = 0; r < 4; ++r) {
            int row = q * 4 + r;
            Xs[row * 520 + coln] = f2bs(gelu_f(acc1[nt][r] + bi));
        }
    }
    __syncthreads();

    // ---- GEMM2: out cols [32w, 32w+32) (B all in registers) ----
    fx4 o0, o1;
#pragma unroll
    for (int r = 0; r < 4; ++r) { o0[r] = 0.0f; o1[r] = 0.0f; }
#pragma unroll
    for (int kk = 0; kk < 16; ++kk) {
        sx8 af = *(const sx8*)(Xs + m16 * 520 + kk * 32 + q * 8);
        o0 = __builtin_amdgcn_mfma_f32_16x16x32_bf16(af, c0a[kk], o0, 0, 0, 0);
        o1 = __builtin_amdgcn_mfma_f32_16x16x32_bf16(af, c1a[kk], o1, 0, 0, 0);
    }
    {
        float bo0 = Woutb[col0], bo1 = Woutb[col1];
#pragma unroll
        for (int r = 0; r < 4; ++r) {
            int row = q * 4 + r;
            hvF[row * 132 + col0] += o0[r] + bo0;
            hvF[row * 132 + col1] += o1[r] + bo1;
        }
    }
    __syncthreads();

    // ---- per-node LN2 + mask, write back ----
    int g = tid >> 5, l32 = tid & 31;
#pragma unroll
    for (int rr = 0; rr < 2; ++rr) {
        int row = g + rr * 8;
        float x0 = hvF[row * 132 + l32];
        float x1 = hvF[row * 132 + l32 + 32];
        float x2 = hvF[row * 132 + l32 + 64];
        float x3 = hvF[row * 132 + l32 + 96];
        float s1 = x0 + x1 + x2 + x3;
        float s2 = x0 * x0 + x1 * x1 + x2 * x2 + x3 * x3;
#pragma unroll
        for (int m = 16; m >= 1; m >>= 1) {
            s1 += __shfl_xor(s1, m, 32);
            s2 += __shfl_xor(s2, m, 32);
        }
        float mean = s1 * (1.0f / 128.0f);
        float var  = s2 * (1.0f / 128.0f) - mean * mean;
        float rstd = rsqrtf(fmaxf(var, 0.0f) + 1e-5f);
        int node = bn * 16 + row;
        float mk = maskV[node];
        float* orow = hv + node * CC;
        orow[l32]      = mk * (g2[l32] * (x0 - mean) * rstd + b2[l32]);
        orow[l32 + 32] = mk * (g2[l32 + 32] * (x1 - mean) * rstd + b2[l32 + 32]);
        orow[l32 + 64] = mk * (g2[l32 + 64] * (x2 - mean) * rstd + b2[l32 + 64]);
        orow[l32 + 96] = mk * (g2[l32 + 96] * (x3 - mean) * rstd + b2[l32 + 96]);
    }
}

extern "C" void kernel_launch(void* const* d_in, const int* in_sizes, int n_in,
                              void* d_out, int out_size, void* d_ws, size_t ws_size,
                              hipStream_t stream) {
    (void)in_sizes; (void)n_in; (void)out_size; (void)ws_size;
    const float* hV    = (const float*)d_in[0];
    const float* hE    = (const float*)d_in[1];
    const int*   Eidx  = (const int*)d_in[2];
    const float* maskV = (const float*)d_in[3];
    const float* maskA = (const float*)d_in[4];
    const float* W1w  = (const float*)d_in[5];
    const float* W1b  = (const float*)d_in[6];
    const float* W2w  = (const float*)d_in[7];
    const float* W2b  = (const float*)d_in[8];
    const float* W3w  = (const float*)d_in[9];
    const float* W3b  = (const float*)d_in[10];
    const float* W11w = (const float*)d_in[11];
    const float* W11b = (const float*)d_in[12];
    const float* W12w = (const float*)d_in[13];
    const float* W12b = (const float*)d_in[14];
    const float* W13w = (const float*)d_in[15];
    const float* W13b = (const float*)d_in[16];
    const float* Winw = (const float*)d_in[17];
    const float* Winb = (const float*)d_in[18];
    const float* Woutw = (const float*)d_in[19];
    const float* Woutb = (const float*)d_in[20];
    const float* g1 = (const float*)d_in[21];
    const float* b1 = (const float*)d_in[22];
    const float* g2 = (const float*)d_in[23];
    const float* b2 = (const float*)d_in[24];
    const float* g3 = (const float*)d_in[25];
    const float* b3 = (const float*)d_in[26];

    short* wt   = (short*)d_ws;                    // 294912 bf16 = 576KB
    float* Pc   = (float*)((char*)d_ws + 589824);  // [4096,128] fp32 = 2MB
    float* Pn   = Pc + (size_t)BB * NN * CC;       // [4096,128] fp32 = 2MB
    float* outV = (float*)d_out;                   // h_V region [4096,128]
    float* outE = outV + (size_t)BB * NN * CC;     // h_E region [4096,48,128]

    prep_weights<<<1152, 256, 0, stream>>>(W1w, W2w, W3w, W11w, W12w, W13w, Winw, Woutw, wt);
    precompute_P<<<256, 256, 0, stream>>>(hV, wt, W1b, Pc, Pn);
    edge_pass<1><<<BB * NN, 256, 0, stream>>>(hV, hE, Eidx,
                                              wt, wt + 49152, W2b, wt + 65536, W3b,
                                              Pc, Pn, maskA, outV, g1, b1, nullptr);
    ffn_kernel<<<256, 256, 0, stream>>>(outV, wt + 163840, Winb, wt + 229376, Woutb, g2, b2, maskV);
    precompute_P<<<256, 256, 0, stream>>>(outV, wt + 81920, W11b, Pc, Pn);
    edge_pass<2><<<BB * NN, 256, 0, stream>>>(outV, hE, Eidx,
                                              wt + 81920, wt + 131072, W12b, wt + 147456, W13b,
                                              Pc, Pn, nullptr, nullptr, g3, b3, outE);
}